// Round 8
// baseline (180.491 us; speedup 1.0000x reference)
//
#include <hip/hip_runtime.h>
#include <stdint.h>
#include <math.h>

#define NB 4
#define NH 16
#define NS 1024
#define ND 64
#define QT 64            // q rows per block
#define KT 64            // k cols per tile
#define NKT (NS/KT)      // 16
#define LDH 72           // f16 row pad: 144B rows, 16B-aligned units
#define SCALE_LOG2E 14426.950408889634f   // 10000 * log2(e); softmax done base-2
#define P_THRESH 5.9604645e-8f            // 2^-24: below this, dropout mask provably irrelevant

typedef _Float16 half8 __attribute__((ext_vector_type(8)));
typedef _Float16 half4 __attribute__((ext_vector_type(4)));
typedef float    f32x4 __attribute__((ext_vector_type(4)));

// XOR-swizzled half-index for a [rows][LDH] f16 LDS array: 16B units within the
// row's first 128B are permuted by row>>2 (T2; same involution on read & write).
__device__ __forceinline__ int swz(int row, int col){
  return row*LDH + ((((col>>3) ^ ((row>>2)&7)))<<3) + (col&7);
}

// ---------------- threefry2x32, key = (0, 42) ----------------
__device__ __forceinline__ void threefry2x32(uint32_t x0, uint32_t x1,
                                             uint32_t &o0, uint32_t &o1){
  const uint32_t ks0 = 0u, ks1 = 42u, ks2 = 0x1BD11BF0u; // 0x1BD11BDA ^ 0 ^ 42
  x0 += ks0; x1 += ks1;
#define TFR(r) { x0 += x1; x1 = __builtin_rotateleft32(x1,(r)); x1 ^= x0; }
  TFR(13) TFR(15) TFR(26) TFR(6)
  x0 += ks1; x1 += ks2 + 1u;
  TFR(17) TFR(29) TFR(16) TFR(24)
  x0 += ks2; x1 += ks0 + 2u;
  TFR(13) TFR(15) TFR(26) TFR(6)
  x0 += ks0; x1 += ks1 + 3u;
  TFR(17) TFR(29) TFR(16) TFR(24)
  x0 += ks1; x1 += ks2 + 4u;
  TFR(13) TFR(15) TFR(26) TFR(6)
  x0 += ks2; x1 += ks0 + 5u;
#undef TFR
  o0 = x0; o1 = x1;
}

// JAX partitionable threefry: bits(i) = o0^o1 of threefry(key, (0, i));
// keep iff (bits>>9) < 0x733333  (uniform < 0.9). Validated rounds 2/4/6/7.
__device__ __forceinline__ uint32_t keep_flat(uint32_t flat){
  uint32_t o0, o1;
  threefry2x32(0u, flat, o0, o1);
  return ((o0 ^ o1) >> 9) < 0x733333u ? 1u : 0u;
}

// MFMA flash attention, fused LAZY dropout. Block = (b,h) x 64-row Q tile; 4 waves.
// QK^T: fp16 2-term split (3 MFMA products) -> fp32 scores; PV: plain fp16 MFMA.
// Dropout threefry evaluated only in slots where __any(p > 2^-24) (conservative:
// p_now >= p_final under online softmax). Prefetch issued AFTER barrier B (R6
// position) — R7's pre-barrier issuance correlated with 199MB scratch traffic.
__global__ __launch_bounds__(256, 3) void attn_mfma(
    const float* __restrict__ Qg, const float* __restrict__ Kg,
    const float* __restrict__ Vg, float* __restrict__ Og)
{
  __shared__ _Float16 Khi[KT*LDH];        // K hi parts, [kc][d] swizzled
  __shared__ _Float16 Klo[KT*LDH];        // K lo parts
  __shared__ _Float16 Vt [ND*LDH];        // V transposed [d][kc] swizzled
  __shared__ _Float16 Pl [4*16*LDH];      // per-wave P [q][kc] swizzled

  const int tid  = threadIdx.x;
  const int wid  = tid >> 6;
  const int lane = tid & 63;
  const int lhi  = lane >> 4;     // 0..3
  const int llo  = lane & 15;

  // bijective XCD swizzle: 1024 blocks, 8 XCDs, 128 contiguous work items each
  const int swzb = (blockIdx.x & 7) * 128 + (blockIdx.x >> 3);
  const int bh  = swzb >> 4;
  const int qt  = swzb & 15;

  // ---- Q A-fragments (registers for whole kernel), hi/lo fp16 split
  half8 qhi[2], qlo[2];
  {
    const float* qsrc = Qg + ((size_t)bh*NS + qt*QT + wid*16 + llo)*ND;
    #pragma unroll
    for (int ks = 0; ks < 2; ++ks) {
      const float* p = qsrc + ks*32 + lhi*8;
      float4 a = *(const float4*)p;
      float4 b = *(const float4*)(p + 4);
      float v[8] = {a.x,a.y,a.z,a.w,b.x,b.y,b.z,b.w};
      #pragma unroll
      for (int j = 0; j < 8; ++j) {
        _Float16 h = (_Float16)v[j];
        qhi[ks][j] = h;
        qlo[ks][j] = (_Float16)(v[j] - (float)h);
      }
    }
  }

  const float* srcK = Kg + (size_t)bh*NS*ND;
  const float* srcV = Vg + (size_t)bh*NS*ND;
  const int frow = tid >> 4;          // 0..15 (global-load row within 256-thread sweep)
  const int fcol = (tid & 15) * 4;    // d offset

  float4 pk[4], pv[4];
  #pragma unroll
  for (int r = 0; r < 4; ++r) {       // prefetch tile 0
    const size_t off = (size_t)(frow + 16*r)*ND + fcol;
    pk[r] = *(const float4*)(srcK + off);
    pv[r] = *(const float4*)(srcV + off);
  }

  f32x4 Oacc[4];
  #pragma unroll
  for (int nt=0;nt<4;++nt){ Oacc[nt][0]=0.f;Oacc[nt][1]=0.f;Oacc[nt][2]=0.f;Oacc[nt][3]=0.f; }
  float m_run[4] = {-INFINITY,-INFINITY,-INFINITY,-INFINITY};   // in scaled-log2 units
  float l_run[4] = {0.f,0.f,0.f,0.f};
  const uint32_t rowflat_base = (uint32_t)(bh*NS + qt*QT + wid*16);

  for (int kt = 0; kt < NKT; ++kt) {
    __syncthreads();   // A: all waves' prior-tile LDS reads complete
    // ---- LDS write phase (consumes pk/pv; compiler inserts vmcnt wait)
    #pragma unroll
    for (int r = 0; r < 4; ++r) {
      const int row = frow + 16*r;    // kc 0..63
      float vals[4] = {pk[r].x, pk[r].y, pk[r].z, pk[r].w};
      half4 h4, l4;
      #pragma unroll
      for (int j = 0; j < 4; ++j) {
        _Float16 h = (_Float16)vals[j];
        h4[j] = h;
        l4[j] = (_Float16)(vals[j] - (float)h);
      }
      const int ki = swz(row, fcol);  // fcol&7 ∈ {0,4}: 8B stays in one 16B unit
      *(half4*)&Khi[ki] = h4;
      *(half4*)&Klo[ki] = l4;
      float vv[4] = {pv[r].x, pv[r].y, pv[r].z, pv[r].w};
      #pragma unroll
      for (int j = 0; j < 4; ++j)
        Vt[swz(fcol+j, row)] = (_Float16)vv[j];   // transposed scalar, swizzled
    }
    __syncthreads();   // B: tiles ready
    // ---- issue next tile's global loads (R6 position; latency hidden under compute)
    if (kt + 1 < NKT) {
      #pragma unroll
      for (int r = 0; r < 4; ++r) {
        const size_t off = (size_t)((kt+1)*KT + frow + 16*r)*ND + fcol;
        pk[r] = *(const float4*)(srcK + off);
        pv[r] = *(const float4*)(srcV + off);
      }
    }

    // ---- QK^T via 3-product fp16 split; acc fp32
    f32x4 S[4];
    #pragma unroll
    for (int nt=0;nt<4;++nt){ S[nt][0]=0.f;S[nt][1]=0.f;S[nt][2]=0.f;S[nt][3]=0.f; }
    #pragma unroll
    for (int ks = 0; ks < 2; ++ks) {
      #pragma unroll
      for (int nt = 0; nt < 4; ++nt) {
        const int ki = swz(nt*16 + llo, ks*32 + lhi*8);
        half8 bh_ = *(const half8*)&Khi[ki];
        half8 bl_ = *(const half8*)&Klo[ki];
        S[nt] = __builtin_amdgcn_mfma_f32_16x16x32_f16(qhi[ks], bh_, S[nt], 0, 0, 0);
        S[nt] = __builtin_amdgcn_mfma_f32_16x16x32_f16(qlo[ks], bh_, S[nt], 0, 0, 0);
        S[nt] = __builtin_amdgcn_mfma_f32_16x16x32_f16(qhi[ks], bl_, S[nt], 0, 0, 0);
      }
    }

    // ---- online softmax in base-2 domain (C-layout: row=4*lhi+reg, col=nt*16+llo)
    float alpha[4];
    #pragma unroll
    for (int reg = 0; reg < 4; ++reg) {
      #pragma unroll
      for (int nt = 0; nt < 4; ++nt) S[nt][reg] *= SCALE_LOG2E;
      float tm = fmaxf(fmaxf(S[0][reg], S[1][reg]), fmaxf(S[2][reg], S[3][reg]));
      #pragma unroll
      for (int off = 1; off < 16; off <<= 1) tm = fmaxf(tm, __shfl_xor(tm, off));
      float mnew = fmaxf(m_run[reg], tm);
      float al   = exp2f(m_run[reg] - mnew);
      m_run[reg] = mnew;
      float ps = 0.f;
      #pragma unroll
      for (int nt = 0; nt < 4; ++nt) {
        float p = exp2f(S[nt][reg] - mnew);
        S[nt][reg] = p;
        ps += p;
      }
      #pragma unroll
      for (int off = 1; off < 16; off <<= 1) ps += __shfl_xor(ps, off);
      l_run[reg] = l_run[reg]*al + ps;
      alpha[reg] = al;
    }
    #pragma unroll
    for (int nt = 0; nt < 4; ++nt)
      #pragma unroll
      for (int reg = 0; reg < 4; ++reg) Oacc[nt][reg] *= alpha[reg];

    // ---- lazy fused dropout + stage P (fp16, swizzled)
    _Float16* Pw = Pl + wid*16*LDH;
    #pragma unroll
    for (int reg = 0; reg < 4; ++reg) {
      const int ql = lhi*4 + reg;
      const uint32_t fb = (rowflat_base + ql)*NS + (uint32_t)(kt*KT + llo);
      #pragma unroll
      for (int nt = 0; nt < 4; ++nt) {
        float p = S[nt][reg];
        if (__any(p > P_THRESH)) {               // wave-uniform branch; ~20% of slots
          p = keep_flat(fb + nt*16) ? p : 0.f;   // exact JAX bits where it matters
        }
        Pw[swz(ql, nt*16 + llo)] = (_Float16)p;
      }
    }

    // ---- PV: O += P(16x64) * V(64x64), fp16 MFMA (same k-map for A and B)
    #pragma unroll
    for (int ks = 0; ks < 2; ++ks) {
      half8 pa = *(const half8*)&Pw[swz(llo, ks*32 + lhi*8)];
      #pragma unroll
      for (int nt = 0; nt < 4; ++nt) {
        half8 vb = *(const half8*)&Vt[swz(nt*16 + llo, ks*32 + lhi*8)];
        Oacc[nt] = __builtin_amdgcn_mfma_f32_16x16x32_f16(pa, vb, Oacc[nt], 0, 0, 0);
      }
    }
  }

  // ---- epilogue: / l_run and / (1-p)
  float sc[4];
  #pragma unroll
  for (int reg = 0; reg < 4; ++reg) sc[reg] = (1.0f/0.9f) / l_run[reg];
  #pragma unroll
  for (int reg = 0; reg < 4; ++reg) {
    const size_t rowoff = ((size_t)bh*NS + qt*QT + wid*16 + lhi*4 + reg)*ND;
    #pragma unroll
    for (int nt = 0; nt < 4; ++nt)
      Og[rowoff + nt*16 + llo] = Oacc[nt][reg] * sc[reg];
  }
}

extern "C" void kernel_launch(void* const* d_in, const int* in_sizes, int n_in,
                              void* d_out, int out_size, void* d_ws, size_t ws_size,
                              hipStream_t stream) {
  const float* x1  = (const float*)d_in[0];   // Q
  const float* kw  = (const float*)d_in[1];   // K
  const float* val = (const float*)d_in[2];   // V
  float* out = (float*)d_out;
  attn_mfma<<<dim3(NB*NH*(NS/QT)), dim3(256), 0, stream>>>(x1, kw, val, out);
}

// Round 9
// 127.516 us; speedup vs baseline: 1.4154x; 1.4154x over previous
//
#include <hip/hip_runtime.h>
#include <stdint.h>
#include <math.h>

#define NB 4
#define NH 16
#define NS 1024
#define ND 64
#define QT 64            // q rows per block
#define KT 64            // k cols per tile
#define NKT (NS/KT)      // 16
#define LDH 72           // f16 row pad: 144B rows, 16B-aligned units
#define SCALE_LOG2E 14426.950408889634f   // 10000 * log2(e); softmax done base-2
#define P_THRESH 5.9604645e-8f            // 2^-24: below this, dropout mask provably irrelevant

typedef _Float16 half8 __attribute__((ext_vector_type(8)));
typedef _Float16 half4 __attribute__((ext_vector_type(4)));
typedef float    f32x4 __attribute__((ext_vector_type(4)));

// XOR-swizzled half-index for a [rows][LDH] f16 LDS array: 16B units within the
// row's first 128B are permuted by row>>2 (T2; same involution on read & write).
__device__ __forceinline__ int swz(int row, int col){
  return row*LDH + ((((col>>3) ^ ((row>>2)&7)))<<3) + (col&7);
}

// ---------------- threefry2x32, key = (0, 42) ----------------
__device__ __forceinline__ void threefry2x32(uint32_t x0, uint32_t x1,
                                             uint32_t &o0, uint32_t &o1){
  const uint32_t ks0 = 0u, ks1 = 42u, ks2 = 0x1BD11BF0u; // 0x1BD11BDA ^ 0 ^ 42
  x0 += ks0; x1 += ks1;
#define TFR(r) { x0 += x1; x1 = __builtin_rotateleft32(x1,(r)); x1 ^= x0; }
  TFR(13) TFR(15) TFR(26) TFR(6)
  x0 += ks1; x1 += ks2 + 1u;
  TFR(17) TFR(29) TFR(16) TFR(24)
  x0 += ks2; x1 += ks0 + 2u;
  TFR(13) TFR(15) TFR(26) TFR(6)
  x0 += ks0; x1 += ks1 + 3u;
  TFR(17) TFR(29) TFR(16) TFR(24)
  x0 += ks1; x1 += ks2 + 4u;
  TFR(13) TFR(15) TFR(26) TFR(6)
  x0 += ks2; x1 += ks0 + 5u;
#undef TFR
  o0 = x0; o1 = x1;
}

// JAX partitionable threefry: bits(i) = o0^o1 of threefry(key, (0, i));
// keep iff (bits>>9) < 0x733333  (uniform < 0.9). Validated rounds 2/4/6/7.
__device__ __forceinline__ uint32_t keep_flat(uint32_t flat){
  uint32_t o0, o1;
  threefry2x32(0u, flat, o0, o1);
  return ((o0 ^ o1) >> 9) < 0x733333u ? 1u : 0u;
}

// MFMA flash attention, fused LAZY dropout (two-pass, phi-free). Block = (b,h) x
// 64-row Q tile; 4 waves. QK^T: fp16 2-term split (3 MFMA) -> fp32; PV: fp16 MFMA.
// Pass 1 stores all P branch-free (ends S live range) + builds need16 mask;
// pass 2 runs threefry only under __any(need) and only WRITES ZEROS (no value
// merges out of the branch => nothing for the allocator to spill — R7/R8's
// 199MB scratch traffic came from the p-phi through the branch).
__global__ __launch_bounds__(256, 3) void attn_mfma(
    const float* __restrict__ Qg, const float* __restrict__ Kg,
    const float* __restrict__ Vg, float* __restrict__ Og)
{
  __shared__ _Float16 Khi[KT*LDH];        // K hi parts, [kc][d] swizzled
  __shared__ _Float16 Klo[KT*LDH];        // K lo parts
  __shared__ _Float16 Vt [ND*LDH];        // V transposed [d][kc] swizzled
  __shared__ _Float16 Pl [4*16*LDH];      // per-wave P [q][kc] swizzled

  const int tid  = threadIdx.x;
  const int wid  = tid >> 6;
  const int lane = tid & 63;
  const int lhi  = lane >> 4;     // 0..3
  const int llo  = lane & 15;

  // bijective XCD swizzle: 1024 blocks, 8 XCDs, 128 contiguous work items each
  const int swzb = (blockIdx.x & 7) * 128 + (blockIdx.x >> 3);
  const int bh  = swzb >> 4;
  const int qt  = swzb & 15;

  // ---- Q A-fragments (registers for whole kernel), hi/lo fp16 split
  half8 qhi[2], qlo[2];
  {
    const float* qsrc = Qg + ((size_t)bh*NS + qt*QT + wid*16 + llo)*ND;
    #pragma unroll
    for (int ks = 0; ks < 2; ++ks) {
      const float* p = qsrc + ks*32 + lhi*8;
      float4 a = *(const float4*)p;
      float4 b = *(const float4*)(p + 4);
      float v[8] = {a.x,a.y,a.z,a.w,b.x,b.y,b.z,b.w};
      #pragma unroll
      for (int j = 0; j < 8; ++j) {
        _Float16 h = (_Float16)v[j];
        qhi[ks][j] = h;
        qlo[ks][j] = (_Float16)(v[j] - (float)h);
      }
    }
  }

  const float* srcK = Kg + (size_t)bh*NS*ND;
  const float* srcV = Vg + (size_t)bh*NS*ND;
  const int frow = tid >> 4;          // 0..15 (global-load row within 256-thread sweep)
  const int fcol = (tid & 15) * 4;    // d offset

  float4 pk[4], pv[4];
  #pragma unroll
  for (int r = 0; r < 4; ++r) {       // prefetch tile 0
    const size_t off = (size_t)(frow + 16*r)*ND + fcol;
    pk[r] = *(const float4*)(srcK + off);
    pv[r] = *(const float4*)(srcV + off);
  }

  f32x4 Oacc[4];
  #pragma unroll
  for (int nt=0;nt<4;++nt){ Oacc[nt][0]=0.f;Oacc[nt][1]=0.f;Oacc[nt][2]=0.f;Oacc[nt][3]=0.f; }
  float m_run[4] = {-INFINITY,-INFINITY,-INFINITY,-INFINITY};   // in scaled-log2 units
  float l_run[4] = {0.f,0.f,0.f,0.f};
  const uint32_t rowflat_base = (uint32_t)(bh*NS + qt*QT + wid*16);

  for (int kt = 0; kt < NKT; ++kt) {
    __syncthreads();   // A: all waves' prior-tile LDS reads complete
    // ---- LDS write phase (consumes pk/pv; compiler inserts vmcnt wait)
    #pragma unroll
    for (int r = 0; r < 4; ++r) {
      const int row = frow + 16*r;    // kc 0..63
      float vals[4] = {pk[r].x, pk[r].y, pk[r].z, pk[r].w};
      half4 h4, l4;
      #pragma unroll
      for (int j = 0; j < 4; ++j) {
        _Float16 h = (_Float16)vals[j];
        h4[j] = h;
        l4[j] = (_Float16)(vals[j] - (float)h);
      }
      const int ki = swz(row, fcol);  // fcol&7 ∈ {0,4}: 8B stays in one 16B unit
      *(half4*)&Khi[ki] = h4;
      *(half4*)&Klo[ki] = l4;
      float vv[4] = {pv[r].x, pv[r].y, pv[r].z, pv[r].w};
      #pragma unroll
      for (int j = 0; j < 4; ++j)
        Vt[swz(fcol+j, row)] = (_Float16)vv[j];   // transposed scalar, swizzled
    }
    __syncthreads();   // B: tiles ready
    // ---- issue next tile's global loads (latency hidden under compute)
    if (kt + 1 < NKT) {
      #pragma unroll
      for (int r = 0; r < 4; ++r) {
        const size_t off = (size_t)((kt+1)*KT + frow + 16*r)*ND + fcol;
        pk[r] = *(const float4*)(srcK + off);
        pv[r] = *(const float4*)(srcV + off);
      }
    }

    // ---- QK^T via 3-product fp16 split; acc fp32
    f32x4 S[4];
    #pragma unroll
    for (int nt=0;nt<4;++nt){ S[nt][0]=0.f;S[nt][1]=0.f;S[nt][2]=0.f;S[nt][3]=0.f; }
    #pragma unroll
    for (int ks = 0; ks < 2; ++ks) {
      #pragma unroll
      for (int nt = 0; nt < 4; ++nt) {
        const int ki = swz(nt*16 + llo, ks*32 + lhi*8);
        half8 bh_ = *(const half8*)&Khi[ki];
        half8 bl_ = *(const half8*)&Klo[ki];
        S[nt] = __builtin_amdgcn_mfma_f32_16x16x32_f16(qhi[ks], bh_, S[nt], 0, 0, 0);
        S[nt] = __builtin_amdgcn_mfma_f32_16x16x32_f16(qlo[ks], bh_, S[nt], 0, 0, 0);
        S[nt] = __builtin_amdgcn_mfma_f32_16x16x32_f16(qhi[ks], bl_, S[nt], 0, 0, 0);
      }
    }

    // ---- online softmax in base-2 domain (C-layout: row=4*lhi+reg, col=nt*16+llo)
    float alpha[4];
    #pragma unroll
    for (int reg = 0; reg < 4; ++reg) {
      #pragma unroll
      for (int nt = 0; nt < 4; ++nt) S[nt][reg] *= SCALE_LOG2E;
      float tm = fmaxf(fmaxf(S[0][reg], S[1][reg]), fmaxf(S[2][reg], S[3][reg]));
      #pragma unroll
      for (int off = 1; off < 16; off <<= 1) tm = fmaxf(tm, __shfl_xor(tm, off));
      float mnew = fmaxf(m_run[reg], tm);
      float al   = exp2f(m_run[reg] - mnew);
      m_run[reg] = mnew;
      float ps = 0.f;
      #pragma unroll
      for (int nt = 0; nt < 4; ++nt) {
        float p = exp2f(S[nt][reg] - mnew);
        S[nt][reg] = p;
        ps += p;
      }
      #pragma unroll
      for (int off = 1; off < 16; off <<= 1) ps += __shfl_xor(ps, off);
      l_run[reg] = l_run[reg]*al + ps;
      alpha[reg] = al;
    }
    #pragma unroll
    for (int nt = 0; nt < 4; ++nt)
      #pragma unroll
      for (int reg = 0; reg < 4; ++reg) Oacc[nt][reg] *= alpha[reg];

    // ---- pass 1: branch-free P staging (fp16, swizzled) + need mask.
    //      Ends S's live range before any control flow.
    _Float16* Pw = Pl + wid*16*LDH;
    uint32_t need16 = 0u;
    #pragma unroll
    for (int reg = 0; reg < 4; ++reg) {
      const int ql = lhi*4 + reg;
      #pragma unroll
      for (int nt = 0; nt < 4; ++nt) {
        float p = S[nt][reg];
        if (p > P_THRESH) need16 |= 1u << (reg*4 + nt);   // branchless cmp+or
        Pw[swz(ql, nt*16 + llo)] = (_Float16)p;
      }
    }
    // ---- pass 2: lazy exact-RNG zeroing. Branch body writes only constants;
    //      no value merges out => no spillable phi.
    #pragma unroll
    for (int reg = 0; reg < 4; ++reg) {
      const int ql = lhi*4 + reg;
      const uint32_t fb = (rowflat_base + ql)*NS + (uint32_t)(kt*KT + llo);
      #pragma unroll
      for (int nt = 0; nt < 4; ++nt) {
        if (__any((int)(need16 & (1u << (reg*4 + nt))))) {
          if (!keep_flat(fb + nt*16))
            Pw[swz(ql, nt*16 + llo)] = (_Float16)0.f;
        }
      }
    }

    // ---- PV: O += P(16x64) * V(64x64), fp16 MFMA (same k-map for A and B)
    #pragma unroll
    for (int ks = 0; ks < 2; ++ks) {
      half8 pa = *(const half8*)&Pw[swz(llo, ks*32 + lhi*8)];
      #pragma unroll
      for (int nt = 0; nt < 4; ++nt) {
        half8 vb = *(const half8*)&Vt[swz(nt*16 + llo, ks*32 + lhi*8)];
        Oacc[nt] = __builtin_amdgcn_mfma_f32_16x16x32_f16(pa, vb, Oacc[nt], 0, 0, 0);
      }
    }
  }

  // ---- epilogue: / l_run and / (1-p)
  float sc[4];
  #pragma unroll
  for (int reg = 0; reg < 4; ++reg) sc[reg] = (1.0f/0.9f) / l_run[reg];
  #pragma unroll
  for (int reg = 0; reg < 4; ++reg) {
    const size_t rowoff = ((size_t)bh*NS + qt*QT + wid*16 + lhi*4 + reg)*ND;
    #pragma unroll
    for (int nt = 0; nt < 4; ++nt)
      Og[rowoff + nt*16 + llo] = Oacc[nt][reg] * sc[reg];
  }
}

extern "C" void kernel_launch(void* const* d_in, const int* in_sizes, int n_in,
                              void* d_out, int out_size, void* d_ws, size_t ws_size,
                              hipStream_t stream) {
  const float* x1  = (const float*)d_in[0];   // Q
  const float* kw  = (const float*)d_in[1];   // K
  const float* val = (const float*)d_in[2];   // V
  float* out = (float*)d_out;
  attn_mfma<<<dim3(NB*NH*(NS/QT)), dim3(256), 0, stream>>>(x1, kw, val, out);
}